// Round 19
// baseline (70.462 us; speedup 1.0000x reference)
//
#include <hip/hip_runtime.h>

// Delay-logistic DDE, forward Euler, d independent scalar components.
// x_{i+1} = x_i * m_i,  m_i = (1+a) - a*th1*y_i;  y_i = x(i-100) (hist = x_0).
// Output: out[j*(N+1) + t] = x_t  (row-major [d, N+1]).
//
// Round 19 = round 14 (best: 31.4us) with ONE change: consumer drain stores
// are NONTEMPORAL (nt bit -> no L2 write-allocate). Theory: the 31-33us
// plateau (4.2TB/s effective vs fill's 6.8) is L2 fetch-before-merge on
// partially-covered 128B lines (~50% of line-touches in the 400B-chunk
// drain are partial). nt stores write through without ownership fetches.
// r17/r18's aligned-x4 drains both regressed ~16us for unexplained reasons
// (complex consumer addressing = high-variance); this is the zero-risk test
// of the same underlying theory. If null/worse: r14 is the structural floor.
//
// Kept verified machinery (r12-r14): producer/consumer waves (1P+3C), zero
// recompute, block owns its 64 rows' 256KB span; h[100] in VGPRs via macro-
// LITERAL indices + (256,1) (rounds 2-5: default occupancy target force-
// spills h); LDS flag sync + lgkmcnt-ONLY fences (r6: cross-lane LDS needs
// explicit ordering; vmcnt never drained in-loop); contiguous row ranges +
// batched 11-row read chunks per consumer (r14).

constexpr int NT   = 1000;          // N steps (setup_inputs: N=1000)
constexpr int NTAU = 100;           // delay = steps per tile
constexpr int NGRP = NT / NTAU;     // 10 tiles
constexpr int NP1  = NT + 1;        // 1001 columns per row
constexpr int COMP = 64;            // components per block (= producer lanes)
constexpr int LSTR = NTAU + 1;      // 101 dwords: odd stride -> conflict-free
constexpr int NCW  = 3;             // consumer waves

// Literal-index repetition macros (SROA-proof: every h index is a literal).
#define R5(F,B)   F(B) F((B)+1) F((B)+2) F((B)+3) F((B)+4)
#define R25(F,B)  R5(F,B) R5(F,(B)+5) R5(F,(B)+10) R5(F,(B)+15) R5(F,(B)+20)
#define R50(F,B)  R25(F,B) R25(F,(B)+25)
#define R100(F)   R50(F,0) R50(F,50)

// LDS-only ordering point: pins compiler order and drains the DS pipe.
// NEVER waits on vmcnt -> global stores keep streaming.
#define LDS_ORDER() do {                                    \
    __builtin_amdgcn_sched_barrier(0);                      \
    asm volatile("s_waitcnt lgkmcnt(0)" ::: "memory");      \
    __builtin_amdgcn_sched_barrier(0);                      \
} while (0)

__global__ __launch_bounds__(256, 1)   // min 1 wave/EU: full VGPR budget
void ndde_kernel(const float* __restrict__ x0,
                 const float* __restrict__ tau,
                 const float* __restrict__ params,
                 float* __restrict__ out)
{
    __shared__ float buf[2][COMP][LSTR];   // 51,712 B double-buffered tile
    __shared__ int   prodf;                // tiles staged by producer
    __shared__ int   consf[NCW];           // tiles consumed, per consumer wave
    const int tid  = threadIdx.x;
    const int wid  = tid >> 6;             // 0 = producer, 1..3 = consumers
    const int lane = tid & 63;
    const int jbase = (int)blockIdx.x * COMP;

    const float dt = 0.01f * tau[0];
    const float a  = dt * params[0];        // dt * theta0
    const float q  = -(a * params[1]);      // -dt*theta0*theta1
    const float p  = 1.0f + a;

    if (tid == 0) { prodf = 0; consf[0] = 0; consf[1] = 0; consf[2] = 0; }
    __syncthreads();                        // flag init only (once; queues empty)

    volatile int* vprod = &prodf;
    volatile int* vcons = consf;

    if (wid == 0) {
        // ---------------- producer ----------------
        float x = x0[jbase + lane];
        float h[NTAU];                      // history; lives in VGPRs
#define INIT_H(K) h[(K)] = x;
        R100(INIT_H)
#define STEP(K) { const float y_ = h[(K)]; h[(K)] = x; x *= fmaf(q, y_, p); }
#define STG(K)  bp[(K)] = h[(K)];

#pragma clang loop unroll(disable)          // keep ~300-instr body I-cache-resident
        for (int g = 0; g < NGRP; ++g) {
            if (g >= 2) {                   // buf[g&1] holds tile g-2: wait consumed
                while (vcons[0] < g - 1 || vcons[1] < g - 1 || vcons[2] < g - 1)
                    __builtin_amdgcn_s_sleep(1);
                LDS_ORDER();                // poll -> overwrite (cross-wave WAR)
            }
            R100(STEP)                      // h[k] = x_{100g+k}
            float* bp = &buf[g & 1][lane][0];
            R100(STG)                       // stage (stride-101: conflict-free)
            LDS_ORDER();                    // data writes drain before flag (RAW)
            *vprod = g + 1;                 // publish tile g
        }
        // Final column t = N: x = x_1000.
        __builtin_nontemporal_store(x, out + (size_t)(jbase + lane) * NP1 + NT);
    } else {
        // ---------------- consumers ----------------
        const int cw    = wid - 1;
        const int start = (cw == 0) ? 0 : (cw == 1) ? 22 : 43;
        const int cnt   = (cw == 0) ? 22 : 21;           // 22+21+21 = 64
        const int lane2 = (lane < 36) ? lane : 35;       // clamp: no LDS OOB
        float* gpb = out + (jbase + start) * NP1 + lane; // row-contiguous range

#pragma clang loop unroll(disable)
        for (int g = 0; g < NGRP; ++g) {
            while (*vprod < g + 1)          // wait for tile g
                __builtin_amdgcn_s_sleep(1);
            LDS_ORDER();                    // poll -> data reads (cross-wave RAW)
            const float* bb = &buf[g & 1][start][0];
            float* gp = gpb + g * NTAU;

            // Two 11-row chunks: batch 22 independent ds_reads, then 22
            // NONTEMPORAL stores (no L2 write-allocate; address order).
            float va[11], vb[11];
#pragma unroll
            for (int i = 0; i < 11; ++i) {
                va[i] = bb[i * LSTR + lane];
                vb[i] = bb[i * LSTR + 64 + lane2];
            }
#pragma unroll
            for (int i = 0; i < 11; ++i) {
                float* rp = gp + i * NP1;
                __builtin_nontemporal_store(va[i], rp);            // t = +0..63
                if (lane < NTAU - 64)
                    __builtin_nontemporal_store(vb[i], rp + 64);   // t = +64..99
            }
#pragma unroll
            for (int i = 0; i < 11; ++i) {
                if (i < cnt - 11) {                 // uniform per wave (10 or 11)
                    va[i] = bb[(11 + i) * LSTR + lane];
                    vb[i] = bb[(11 + i) * LSTR + 64 + lane2];
                }
            }
#pragma unroll
            for (int i = 0; i < 11; ++i) {
                if (i < cnt - 11) {
                    float* rp = gp + (11 + i) * NP1;
                    __builtin_nontemporal_store(va[i], rp);
                    if (lane < NTAU - 64)
                        __builtin_nontemporal_store(vb[i], rp + 64);
                }
            }
            LDS_ORDER();                    // ds_reads drained (stores NOT waited)
            vcons[cw] = g + 1;              // release buf[g&1]
        }
    }
}

extern "C" void kernel_launch(void* const* d_in, const int* in_sizes, int n_in,
                              void* d_out, int out_size, void* d_ws, size_t ws_size,
                              hipStream_t stream) {
    const float* x0     = (const float*)d_in[0];
    const float* tau    = (const float*)d_in[1];
    const float* params = (const float*)d_in[2];
    float* out = (float*)d_out;
    const int d = in_sizes[0];              // 32768
    const int nblocks = d / COMP;           // 512 blocks x 256 threads
    ndde_kernel<<<nblocks, 256, 0, stream>>>(x0, tau, params, out);
}

// Round 20
// 47.051 us; speedup vs baseline: 1.4976x; 1.4976x over previous
//
#include <hip/hip_runtime.h>

// Delay-logistic DDE, forward Euler, d independent scalar components.
// x_{i+1} = x_i * m_i,  m_i = (1+a) - a*th1*y_i;  y_i = x(i-100) (hist = x_0).
// Output: out[j*(N+1) + t] = x_t  (row-major [d, N+1]).
//
// Round 20: WHOLE-LINE drain. r19 (nontemporal) ran 2.2x WORSE -> proves the
// plateau's mechanism is partial-128B-line store handling: L2 write-allocate
// must FETCH a missing line before merging a partial store (hidden ~40-80MB
// of line fetches in the r14 pattern = the 4.2-vs-6.8TB/s gap). r18 never
// tested this (16B-aligned != 128B-line-aligned). Here every steady-state
// store covers ONLY whole lines:
//   col c of row j is line-aligned iff c ≡ -9j (mod 32)  [4004 = 125*32+4,
//   (1001j+c)*4 ≡ 0 mod 128 <=> 9j+c ≡ 0 mod 32]; jbase*9 ≡ 0 (mod 32).
//   Per-row phase ranges snapped to line boundaries: P(ph,r) = 200ph -
//   ((8ph+9r)&31); producer stages a 31-col prefix so [P(ph,r),P(ph+1,r))
//   is always in buf. One 48/56-lane dwordx4 store per row per phase.
//   LDS stride 237 (13 mod 32, gcd=1: bank-clean) makes every consumer
//   ds_read_b128 16B-aligned: idx = r*237 + (c-200ph) + 32, and
//   r*237 - (8ph+9r) ≡ 0 (mod 4).
//   Partials: only row head (<=31 cols, ph0) and tail (<=31, ph4) -- 2 per
//   ROW total; they merge with adjacent rows' stores in L2 (same block).
// Kept: r16 skeleton -- 1P+3C waves, zero recompute, LDS flags + lgkmcnt-only
// fences (vmcnt never drained in-loop), h[100] in VGPRs via macro-LITERAL
// indices + (256,1), batched 2-row reads (r14).

constexpr int NT   = 1000;          // N steps (setup_inputs: N=1000)
constexpr int NTAU = 100;           // delay = ring size
constexpr int NPH  = 5;             // phases (2 tiles each)
constexpr int PCOL = 200;           // columns per phase
constexpr int NP1  = NT + 1;        // 1001 columns per row
constexpr int COMP = 64;            // components per block (= producer lanes)
constexpr int LSTR = 237;           // 1 pad + 31 prefix + 200 cols + 1 final + slack
constexpr int NCW  = 3;             // consumer waves

// Literal-index repetition macros (SROA-proof: every h index is a literal).
#define R5(F,B)   F(B) F((B)+1) F((B)+2) F((B)+3) F((B)+4)
#define R25(F,B)  R5(F,B) R5(F,(B)+5) R5(F,(B)+10) R5(F,(B)+15) R5(F,(B)+20)
#define R31(F,B)  R25(F,B) R5(F,(B)+25) F((B)+30)
#define R50(F,B)  R25(F,B) R25(F,(B)+25)
#define R100(F)   R50(F,0) R50(F,50)

// LDS-only ordering point: pins compiler order and drains the DS pipe.
// NEVER waits on vmcnt -> global stores keep streaming.
#define LDS_ORDER() do {                                    \
    __builtin_amdgcn_sched_barrier(0);                      \
    asm volatile("s_waitcnt lgkmcnt(0)" ::: "memory");      \
    __builtin_amdgcn_sched_barrier(0);                      \
} while (0)

__global__ __launch_bounds__(256, 1)   // min 1 wave/EU: full VGPR budget
void ndde_kernel(const float* __restrict__ x0,
                 const float* __restrict__ tau,
                 const float* __restrict__ params,
                 float* __restrict__ out)
{
    __shared__ float buf[2][COMP][LSTR];   // 121,344 B double-buffered phase image
    __shared__ int   prodf;                // phases published
    __shared__ int   consf[NCW];           // phases consumed, per consumer wave
    const int tid  = threadIdx.x;
    const int wid  = tid >> 6;             // 0 = producer, 1..3 = consumers
    const int lane = tid & 63;
    const int jbase = (int)blockIdx.x * COMP;   // 64-aligned: 9*jbase ≡ 0 mod 32

    const float dt = 0.01f * tau[0];
    const float a  = dt * params[0];        // dt * theta0
    const float q  = -(a * params[1]);      // -dt*theta0*theta1
    const float p  = 1.0f + a;

    if (tid == 0) { prodf = 0; consf[0] = 0; consf[1] = 0; consf[2] = 0; }
    __syncthreads();                        // flag init only (once; queues empty)

    volatile int* vprod = &prodf;
    volatile int* vcons = consf;

    if (wid == 0) {
        // ---------------- producer ----------------
        float x = x0[jbase + lane];
        float h[NTAU];                      // history ring; lives in VGPRs
#define INIT_H(K) h[(K)] = x;
        R100(INIT_H)
#define STEP(K) { const float y_ = h[(K)]; h[(K)] = x; x *= fmaf(q, y_, p); }
#define PFX(K)  bp[1+(K)]   = h[69+(K)];   // cols 200ph-31..-1 (prev tile's h)
#define STG0(K) bp[32+(K)]  = h[(K)];      // phase cols 0..99   (idx = c-200ph+32)
#define STG1(K) bp[132+(K)] = h[(K)];      // phase cols 100..199

#pragma clang loop unroll(disable)          // keep body I-cache-resident
        for (int ph = 0; ph < NPH; ++ph) {
            if (ph >= 2) {                  // buf[ph&1] holds phase ph-2: wait consumed
                while (vcons[0] < ph - 1 || vcons[1] < ph - 1 || vcons[2] < ph - 1)
                    __builtin_amdgcn_s_sleep(1);
                LDS_ORDER();                // poll -> overwrite (cross-wave WAR)
            }
            float* bp = &buf[ph & 1][lane][0];
            if (ph > 0) { R31(PFX, 0) }     // h = prev phase's 2nd tile here
            R100(STEP)                      // h[k] = x_{200ph+k}
            R100(STG0)
            R100(STEP)                      // h[k] = x_{200ph+100+k}
            R100(STG1)
            if (ph == NPH - 1) bp[232] = x; // col 1000 = x_N into the image
            LDS_ORDER();                    // data writes drain before flag (RAW)
            *vprod = ph + 1;                // publish phase
        }
    } else {
        // ---------------- consumers ----------------
        const int cw = wid - 1;
        const int r0 = (cw == 0) ? 0 : (cw == 1) ? 22 : 43;
        const int rn = (cw == 0) ? 22 : 21;              // 22+21+21 = 64

#pragma clang loop unroll(disable)
        for (int ph = 0; ph < NPH; ++ph) {
            while (*vprod < ph + 1)         // wait for phase
                __builtin_amdgcn_s_sleep(1);
            LDS_ORDER();                    // poll -> data reads (cross-wave RAW)
            const float* bb = &buf[ph & 1][0][0];

            // Per row r: whole-line range [lo, hi), both ≡ -9r (mod 32);
            // one dwordx4 store (48/56 lanes) covering ONLY full 128B lines.
            for (int rr = 0; rr < rn; rr += 2) {
                const int  r1  = r0 + rr;
                const bool two = (rr + 1 < rn);
                const int  r2  = two ? (r1 + 1) : r1;

                int lo1, hi1, lo2, hi2;
                if (ph == 0) {
                    lo1 = (32 - ((9 * r1) & 31)) & 31;          // a_r
                    lo2 = (32 - ((9 * r2) & 31)) & 31;
                    hi1 = PCOL - ((8 + 9 * r1) & 31);
                    hi2 = PCOL - ((8 + 9 * r2) & 31);
                } else if (ph < NPH - 1) {
                    lo1 = PCOL * ph - ((8 * ph + 9 * r1) & 31);
                    lo2 = PCOL * ph - ((8 * ph + 9 * r2) & 31);
                    hi1 = PCOL * (ph + 1) - ((8 * (ph + 1) + 9 * r1) & 31);
                    hi2 = PCOL * (ph + 1) - ((8 * (ph + 1) + 9 * r2) & 31);
                } else {
                    lo1 = PCOL * 4 - ((9 * r1) & 31);           // 8*4 ≡ 0 mod 32
                    lo2 = PCOL * 4 - ((9 * r2) & 31);
                    hi1 = lo1 + (((NT + 1) - lo1) & ~31);
                    hi2 = lo2 + (((NT + 1) - lo2) & ~31);
                }
                const int nl1 = (hi1 - lo1) >> 2;               // 40..56 lanes
                const int nl2 = (hi2 - lo2) >> 2;

                // 16B-aligned LDS b128 reads (batched), then whole-line stores.
                const float4* lp1 = (const float4*)(bb + r1 * LSTR + lo1 - PCOL * ph + 32);
                const float4* lp2 = (const float4*)(bb + r2 * LSTR + lo2 - PCOL * ph + 32);
                float4 v1, v2;
                if (lane < nl1) v1 = lp1[lane];
                if (two && lane < nl2) v2 = lp2[lane];

                float* gp1 = out + (size_t)(jbase + r1) * NP1 + lo1;
                float* gp2 = out + (size_t)(jbase + r2) * NP1 + lo2;
                if (lane < nl1) *(float4*)(gp1 + 4 * lane) = v1;   // 128B-aligned
                if (two && lane < nl2) *(float4*)(gp2 + 4 * lane) = v2;

                if (ph == 0) {              // head partial: cols 0..lo-1 (<=31)
                    if (lane < lo1)
                        out[(size_t)(jbase + r1) * NP1 + lane] = bb[r1 * LSTR + 32 + lane];
                    if (two && lane < lo2)
                        out[(size_t)(jbase + r2) * NP1 + lane] = bb[r2 * LSTR + 32 + lane];
                } else if (ph == NPH - 1) { // tail partial: cols hi..1000 (<=31)
                    const int tc1 = (NT + 1) - hi1;
                    const int tc2 = (NT + 1) - hi2;
                    if (lane < tc1)
                        out[(size_t)(jbase + r1) * NP1 + hi1 + lane] =
                            bb[r1 * LSTR + (hi1 - 800) + 32 + lane];
                    if (two && lane < tc2)
                        out[(size_t)(jbase + r2) * NP1 + hi2 + lane] =
                            bb[r2 * LSTR + (hi2 - 800) + 32 + lane];
                }
            }
            LDS_ORDER();                    // ds_reads drained (stores NOT waited)
            vcons[cw] = ph + 1;             // release buf[ph&1]
        }
    }
}

extern "C" void kernel_launch(void* const* d_in, const int* in_sizes, int n_in,
                              void* d_out, int out_size, void* d_ws, size_t ws_size,
                              hipStream_t stream) {
    const float* x0     = (const float*)d_in[0];
    const float* tau    = (const float*)d_in[1];
    const float* params = (const float*)d_in[2];
    float* out = (float*)d_out;
    const int d = in_sizes[0];              // 32768
    const int nblocks = d / COMP;           // 512 blocks x 256 threads
    ndde_kernel<<<nblocks, 256, 0, stream>>>(x0, tau, params, out);
}

// Round 21
// 30.753 us; speedup vs baseline: 2.2912x; 1.5299x over previous
//
#include <hip/hip_runtime.h>

// Delay-logistic DDE, forward Euler, d independent scalar components.
// x_{i+1} = x_i * m_i,  m_i = (1+a) - a*th1*y_i;  y_i = x(i-100) (hist = x_0).
// Output: out[j*(N+1) + t] = x_t  (row-major [d, N+1]).
//
// Round 21 = round 14 (best: 31.4us) with 7 CONSUMER WAVES instead of 3
// (block = 512 threads = 1 producer + 7 consumers; 14 store streams/CU).
// Why: store-stream CONCURRENCY. The spilling kernels (r2/r8) sustained
// ~5.0 TB/s of writes with ~12 streams/CU; clean r14 sustains only 4.2 with
// 6. All pattern-level theories are falsified (aligned r20 / misaligned r14
// / nt r19 ordered wrong for any line-RMW model; density r16 null; sync r13
// null). Remaining model: each stream stalls on L2 round-trips between
// bursts; more independent streams -> higher write-port duty cycle.
//
// Kept verified machinery (r12-r14): producer/consumer waves, zero
// recompute, block owns its 64 rows' 256KB span; h[100] in VGPRs via macro-
// LITERAL indices + (512,1) (rounds 2-5: default occupancy target force-
// spills h); LDS flag sync + lgkmcnt-ONLY fences (r6: cross-lane LDS needs
// explicit ordering; vmcnt never drained in-loop); contiguous row ranges +
// batched read chunks per consumer (r14); NO nontemporal (r19: 2.2x worse).

constexpr int NT   = 1000;          // N steps (setup_inputs: N=1000)
constexpr int NTAU = 100;           // delay = steps per tile
constexpr int NGRP = NT / NTAU;     // 10 tiles
constexpr int NP1  = NT + 1;        // 1001 columns per row
constexpr int COMP = 64;            // components per block (= producer lanes)
constexpr int LSTR = NTAU + 1;      // 101 dwords: odd stride -> conflict-free
constexpr int NCW  = 7;             // consumer waves (r14 had 3)

// Literal-index repetition macros (SROA-proof: every h index is a literal).
#define R5(F,B)   F(B) F((B)+1) F((B)+2) F((B)+3) F((B)+4)
#define R25(F,B)  R5(F,B) R5(F,(B)+5) R5(F,(B)+10) R5(F,(B)+15) R5(F,(B)+20)
#define R50(F,B)  R25(F,B) R25(F,(B)+25)
#define R100(F)   R50(F,0) R50(F,50)

// LDS-only ordering point: pins compiler order and drains the DS pipe.
// NEVER waits on vmcnt -> global stores keep streaming.
#define LDS_ORDER() do {                                    \
    __builtin_amdgcn_sched_barrier(0);                      \
    asm volatile("s_waitcnt lgkmcnt(0)" ::: "memory");      \
    __builtin_amdgcn_sched_barrier(0);                      \
} while (0)

__global__ __launch_bounds__(512, 1)   // min 1 wave/EU: full VGPR budget
void ndde_kernel(const float* __restrict__ x0,
                 const float* __restrict__ tau,
                 const float* __restrict__ params,
                 float* __restrict__ out)
{
    __shared__ float buf[2][COMP][LSTR];   // 51,712 B double-buffered tile
    __shared__ int   prodf;                // tiles staged by producer
    __shared__ int   consf[NCW];           // tiles consumed, per consumer wave
    const int tid  = threadIdx.x;
    const int wid  = tid >> 6;             // 0 = producer, 1..7 = consumers
    const int lane = tid & 63;
    const int jbase = (int)blockIdx.x * COMP;

    const float dt = 0.01f * tau[0];
    const float a  = dt * params[0];        // dt * theta0
    const float q  = -(a * params[1]);      // -dt*theta0*theta1
    const float p  = 1.0f + a;

    if (tid < NCW + 1) {                    // init flags
        if (tid == 0) prodf = 0;
        else consf[tid - 1] = 0;
    }
    __syncthreads();                        // flag init only (once; queues empty)

    volatile int* vprod = &prodf;
    volatile int* vcons = consf;

    if (wid == 0) {
        // ---------------- producer ----------------
        float x = x0[jbase + lane];
        float h[NTAU];                      // history; lives in VGPRs
#define INIT_H(K) h[(K)] = x;
        R100(INIT_H)
#define STEP(K) { const float y_ = h[(K)]; h[(K)] = x; x *= fmaf(q, y_, p); }
#define STG(K)  bp[(K)] = h[(K)];

#pragma clang loop unroll(disable)          // keep ~300-instr body I-cache-resident
        for (int g = 0; g < NGRP; ++g) {
            if (g >= 2) {                   // buf[g&1] holds tile g-2: wait consumed
                for (;;) {
                    int done = 1;
#pragma unroll
                    for (int c = 0; c < NCW; ++c)
                        if (vcons[c] < g - 1) done = 0;
                    if (done) break;
                    __builtin_amdgcn_s_sleep(1);
                }
                LDS_ORDER();                // poll -> overwrite (cross-wave WAR)
            }
            R100(STEP)                      // h[k] = x_{100g+k}
            float* bp = &buf[g & 1][lane][0];
            R100(STG)                       // stage (stride-101: conflict-free)
            LDS_ORDER();                    // data writes drain before flag (RAW)
            *vprod = g + 1;                 // publish tile g
        }
        // Final column t = N: x = x_1000.
        out[(size_t)(jbase + lane) * NP1 + NT] = x;
    } else {
        // ---------------- consumers ----------------
        const int cw    = wid - 1;                       // 0..6
        const int start = (cw == 0) ? 0 : 10 + 9 * (cw - 1);
        const int cnt   = (cw == 0) ? 10 : 9;            // 10 + 6*9 = 64
        const int lane2 = (lane < 36) ? lane : 35;       // clamp: no LDS OOB
        float* gpb = out + (jbase + start) * NP1 + lane; // row-contiguous range

#pragma clang loop unroll(disable)
        for (int g = 0; g < NGRP; ++g) {
            while (*vprod < g + 1)          // wait for tile g
                __builtin_amdgcn_s_sleep(1);
            LDS_ORDER();                    // poll -> data reads (cross-wave RAW)
            const float* bb = &buf[g & 1][start][0];
            float* gp = gpb + g * NTAU;

            // Batch all rows' reads (<=20 regs), then all stores in address
            // order (one lgkm wait per tile; stores stream, never vmcnt-waited).
            float va[10], vb[10];
#pragma unroll
            for (int i = 0; i < 10; ++i) {
                if (i < cnt) {
                    va[i] = bb[i * LSTR + lane];
                    vb[i] = bb[i * LSTR + 64 + lane2];
                }
            }
#pragma unroll
            for (int i = 0; i < 10; ++i) {
                if (i < cnt) {
                    float* rp = gp + i * NP1;
                    rp[0] = va[i];                        // t = 100g + 0..63
                    if (lane < NTAU - 64) rp[64] = vb[i]; // t = 100g + 64..99
                }
            }
            LDS_ORDER();                    // ds_reads drained (stores NOT waited)
            vcons[cw] = g + 1;              // release buf[g&1]
        }
    }
}

extern "C" void kernel_launch(void* const* d_in, const int* in_sizes, int n_in,
                              void* d_out, int out_size, void* d_ws, size_t ws_size,
                              hipStream_t stream) {
    const float* x0     = (const float*)d_in[0];
    const float* tau    = (const float*)d_in[1];
    const float* params = (const float*)d_in[2];
    float* out = (float*)d_out;
    const int d = in_sizes[0];              // 32768
    const int nblocks = d / COMP;           // 512 blocks x 512 threads
    ndde_kernel<<<nblocks, 512, 0, stream>>>(x0, tau, params, out);
}